// Round 7
// baseline (775.468 us; speedup 1.0000x reference)
//
#include <hip/hip_runtime.h>

#define IN_F 4096
#define OUT_F 11008
#define NGROUPS 32
#define M_TOTAL 8192
#define BM 256
#define BN 256
#define BK 64
#define NKT (IN_F / BK)  // 64 K-tiles, 32 iters of 2 tiles / 8 phases

typedef _Float16 half_t;
typedef __attribute__((ext_vector_type(8))) _Float16 half8;
typedef __attribute__((ext_vector_type(4))) _Float16 half4v;
typedef __attribute__((ext_vector_type(4))) float f32x4;
typedef __attribute__((ext_vector_type(4))) int i32x4;

typedef __attribute__((address_space(1))) const void gvoid_t;
typedef __attribute__((address_space(3))) void lvoid_t;

// ---------------- prepass 1: x fp32 -> fp16 (RTNE) ----------------
__global__ void convert_x_k(const float* __restrict__ x, half_t* __restrict__ xh) {
  const int n4 = M_TOTAL * IN_F / 4;
  int stride = gridDim.x * blockDim.x;
  for (int i = blockIdx.x * blockDim.x + threadIdx.x; i < n4; i += stride) {
    f32x4 v = __builtin_nontemporal_load((const f32x4*)x + i);
    half4v h;
    h[0] = (_Float16)v[0]; h[1] = (_Float16)v[1];
    h[2] = (_Float16)v[2]; h[3] = (_Float16)v[3];
    ((half4v*)xh)[i] = h;
  }
}

// ---------------- prepass 2: W (int32-materialized int8) * group scale -> fp16 ----------
__global__ void dequant_w_k(const int* __restrict__ wq,
                            const float* __restrict__ scales,
                            half_t* __restrict__ wh) {
  int row = blockIdx.x;
  int t = threadIdx.x;  // 512 threads, 8 weights each
  size_t base = (size_t)row * IN_F + (size_t)t * 8;
  float s = scales[row * NGROUPS + (t >> 4)];
  i32x4 q0 = __builtin_nontemporal_load((const i32x4*)(wq + base));
  i32x4 q1 = __builtin_nontemporal_load((const i32x4*)(wq + base) + 1);
  half8 h;
#pragma unroll
  for (int j = 0; j < 4; ++j) h[j] = (_Float16)((float)q0[j] * s);
#pragma unroll
  for (int j = 0; j < 4; ++j) h[4 + j] = (_Float16)((float)q1[j] * s);
  *(half8*)(wh + base) = h;
}

// ---------------- 256x256 GEMM, m201-faithful 8-phase schedule ----------------
// LDS [slot][op][kh][256x32] fp16, 64 B rows, T2 swizzle c ^= (row&6)<<3 (both sides).
// Units = 16 KB half-tiles (op,kh). 1 stage/phase; vmcnt(6) at ph4 & ph8 ONLY.
// Stage map (iter u, t0=2u, t1=2u+1, n0=t0+2, n1=t1+2):
//   ph1:Ak1(t1)->s1  ph2:Bk0(n0)->s0  ph3:Ak0(n0)->s0  ph4:Bk1(n0)->s0 +v6
//   ph5:Ak1(n0)->s0  ph6:Bk0(n1)->s1  ph7:Ak0(n1)->s1  ph8:Bk1(n1)->s1 +v6
// Each target region lgkm-drained at a strictly-prior barrier; each fence retires
// exactly the units read before the next fence (issue-order audited).
// Phase: [rd 4-8 b128][stage][bar][lgkm0][setprio1][16 MFMA][setprio0][fence?][bar]

__device__ __forceinline__ void rd4(half8 (&d)[4], const char* base) {
#pragma unroll
  for (int i = 0; i < 4; ++i) d[i] = *(const half8*)(base + i * 1024);
}

__device__ __forceinline__ void mfma16(f32x4 (&acc)[8][4], const half8 (&a)[4],
                                       const half8 (&b)[4], int mh) {
#pragma unroll
  for (int i = 0; i < 4; ++i)
#pragma unroll
    for (int j = 0; j < 4; ++j)
      acc[mh * 4 + i][j] =
          __builtin_amdgcn_mfma_f32_16x16x32_f16(a[i], b[j], acc[mh * 4 + i][j], 0, 0, 0);
}

#define BAR() __builtin_amdgcn_s_barrier()
#define SB0() __builtin_amdgcn_sched_barrier(0)
#define PRIO1() __builtin_amdgcn_s_setprio(1)
#define PRIO0() __builtin_amdgcn_s_setprio(0)
#define VMCNT(N) asm volatile("s_waitcnt vmcnt(" #N ")" ::: "memory")
#define LGKM(N) asm volatile("s_waitcnt lgkmcnt(" #N ")" ::: "memory")

#define STAGE(OP, KH, KT, S)                                                          \
  do {                                                                                \
    const half_t* g_ = ((OP) ? pBsrc : pAsrc) + (KT) * 64 + (KH) * 32;                \
    char* d_ = (char*)&lds[S][OP][KH][0] + wvoff;                                     \
    __builtin_amdgcn_global_load_lds((gvoid_t*)g_, (lvoid_t*)d_, 16, 0, 0);           \
    __builtin_amdgcn_global_load_lds((gvoid_t*)(g_ + 128 * IN_F),                     \
                                     (lvoid_t*)(d_ + 8192), 16, 0, 0);                \
  } while (0)

// Full phase: reads + stage + m201 barrier/lgkm/prio skeleton. FENCE: 0=none,1=vmcnt6
#define PH(SL, KH, MH, RB, SOP, SKH, SKT, SSL, FENCE)                  \
  do {                                                                 \
    rd4(a, (const char*)&lds[SL][0][KH][0] + aoff + (MH) * 4096);      \
    if (RB) rd4(b, (const char*)&lds[SL][1][KH][0] + boff);            \
    STAGE(SOP, SKH, SKT, SSL);                                         \
    SB0(); BAR();                                                      \
    LGKM(0); SB0(); PRIO1();                                           \
    mfma16(acc, a, b, MH);                                             \
    PRIO0();                                                           \
    if (FENCE) VMCNT(6);                                               \
    BAR(); SB0();                                                      \
  } while (0)

// No-stage phase for the peeled last iteration. FENCE: 0=none, 2=vmcnt0
#define PHN(SL, KH, MH, RB, FENCE)                                     \
  do {                                                                 \
    rd4(a, (const char*)&lds[SL][0][KH][0] + aoff + (MH) * 4096);      \
    if (RB) rd4(b, (const char*)&lds[SL][1][KH][0] + boff);            \
    SB0(); BAR();                                                      \
    LGKM(0); SB0(); PRIO1();                                           \
    mfma16(acc, a, b, MH);                                             \
    PRIO0();                                                           \
    if (FENCE) VMCNT(0);                                               \
    BAR(); SB0();                                                      \
  } while (0)

__global__ __launch_bounds__(512, 1) void gemm_k(const half_t* __restrict__ A,
                                                 const half_t* __restrict__ B,
                                                 const float* __restrict__ bias,
                                                 float* __restrict__ C) {
  __shared__ __align__(16) half_t lds[2][2][2][8192];  // 128 KiB

  const int tid = threadIdx.x;
  const int lane = tid & 63;
  const int wv = tid >> 6;
  const int wm = wv >> 2;
  const int wn = wv & 3;
  const int wvoff = wv << 10;

  // Band-rasterized, XCD-aware map (nwg = 1376 = 8*172, bijective):
  // bands of 32 bm x 4 bn, bn fastest -> co-resident window shares panels in L2.
  const int nwg = gridDim.x;
  const int perx = nwg >> 3;  // 172
  const int L = ((int)blockIdx.x & 7) * perx + ((int)blockIdx.x >> 3);
  const int band = L >> 7;
  const int rr_ = L & 127;
  const int bn0 = band << 2;
  const int cols = (43 - bn0) < 4 ? (43 - bn0) : 4;
  const int bm = rr_ / cols;
  const int bn = bn0 + rr_ % cols;
  const int row0 = bm * BM;
  const int col0 = bn * BN;

  // staging source (pre-swizzled; involution c ^= (row&6)<<3)
  const int c16 = (tid & 3) * 16;
  const int srow = tid >> 2;
  const int clog = c16 ^ ((srow & 6) << 3);
  const int kidx = clog >> 1;
  const half_t* pAsrc = A + (size_t)(row0 + srow) * IN_F + kidx;
  const half_t* pBsrc = B + (size_t)(col0 + srow) * IN_F + kidx;

  // fragment read offsets (swizzled); frag stride 16 rows * 64 B = 1024
  const int r16 = lane & 15;
  const int kg = lane >> 4;
  const int arow = wm * 128 + r16;
  const int brow = wn * 64 + r16;
  const int aoff = arow * 64 + ((kg * 16) ^ ((arow & 6) << 3));
  const int boff = brow * 64 + ((kg * 16) ^ ((brow & 6) << 3));

  f32x4 acc[8][4];
#pragma unroll
  for (int m = 0; m < 8; ++m)
#pragma unroll
    for (int n = 0; n < 4; ++n) acc[m][n] = (f32x4){0.f, 0.f, 0.f, 0.f};

  // prologue: tile0 all 4 units + tile1 {Ak0,Bk0,Bk1} (Ak1(1) staged at ph1 of iter 0).
  // vmcnt(6): retire tile0's 4 units, keep 3 tile-1 units in flight.
  STAGE(0, 0, 0, 0);
  STAGE(1, 0, 0, 0);
  STAGE(0, 1, 0, 0);
  STAGE(1, 1, 0, 0);
  STAGE(0, 0, 1, 1);
  STAGE(1, 0, 1, 1);
  STAGE(1, 1, 1, 1);
  VMCNT(6);
  BAR();
  SB0();

  half8 a[4], b[4];
  for (int u = 0; u < 31; ++u) {
    const int t1 = 2 * u + 1, n0 = 2 * u + 2, n1 = 2 * u + 3;
    PH(0, 0, 0, 1, 0, 1, t1, 1, 0);  // ph1: rd Ak0mh0+Bk0(s0); stage Ak1(t1)->s1
    PH(0, 0, 1, 0, 1, 0, n0, 0, 0);  // ph2: rd Ak0mh1;         stage Bk0(n0)->s0
    PH(0, 1, 0, 1, 0, 0, n0, 0, 0);  // ph3: rd Ak1mh0+Bk1;     stage Ak0(n0)->s0
    PH(0, 1, 1, 0, 1, 1, n0, 0, 1);  // ph4: rd Ak1mh1;         stage Bk1(n0); v6
    PH(1, 0, 0, 1, 0, 1, n0, 0, 0);  // ph5: rd (s1);           stage Ak1(n0)->s0
    PH(1, 0, 1, 0, 1, 0, n1, 1, 0);  // ph6:                    stage Bk0(n1)->s1
    PH(1, 1, 0, 1, 0, 0, n1, 1, 0);  // ph7:                    stage Ak0(n1)->s1
    PH(1, 1, 1, 0, 1, 1, n1, 1, 1);  // ph8:                    stage Bk1(n1); v6
  }
  {  // peeled iter 31 (tiles 62,63): ph1 stages Ak1(63); vmcnt(0) at ph4; then dry
    PH(0, 0, 0, 1, 0, 1, 63, 1, 0);
    PHN(0, 0, 1, 0, 0);
    PHN(0, 1, 0, 1, 0);
    PHN(0, 1, 1, 0, 2);  // vmcnt(0): all of tile 63 resident
    PHN(1, 0, 0, 1, 0);
    PHN(1, 0, 1, 0, 0);
    PHN(1, 1, 0, 1, 0);
    PHN(1, 1, 1, 0, 0);
  }

  // epilogue: fp16 rounding + fp16 bias add (reference numerics), NT fp32 store
  const int kg4 = kg * 4;
#pragma unroll
  for (int nf = 0; nf < 4; ++nf) {
    int col = col0 + wn * 64 + nf * 16 + r16;
    _Float16 bh = (_Float16)bias[col];
#pragma unroll
    for (int mf = 0; mf < 8; ++mf) {
      int rb = row0 + wm * 128 + mf * 16 + kg4;
#pragma unroll
      for (int r = 0; r < 4; ++r) {
        _Float16 v = (_Float16)acc[mf][nf][r] + bh;
        __builtin_nontemporal_store((float)v, &C[(size_t)(rb + r) * OUT_F + col]);
      }
    }
  }
}

// ---------------- emergency fallback (ws too small) ----------------
__global__ void naive_k(const float* __restrict__ x, const int* __restrict__ wq,
                        const float* __restrict__ scales, const float* __restrict__ bias,
                        float* __restrict__ out) {
  long idx = (long)blockIdx.x * blockDim.x + threadIdx.x;
  if (idx >= (long)M_TOTAL * OUT_F) return;
  int m = (int)(idx / OUT_F);
  int n = (int)(idx % OUT_F);
  float acc = 0.f;
  for (int g = 0; g < NGROUPS; ++g) {
    float s = scales[n * NGROUPS + g];
    for (int k = g * 128; k < (g + 1) * 128; ++k) {
      _Float16 xv = (_Float16)x[(size_t)m * IN_F + k];
      _Float16 wv = (_Float16)((float)wq[(size_t)n * IN_F + k] * s);
      acc += (float)xv * (float)wv;
    }
  }
  _Float16 r = (_Float16)acc + (_Float16)bias[n];
  out[idx] = (float)r;
}

extern "C" void kernel_launch(void* const* d_in, const int* in_sizes, int n_in,
                              void* d_out, int out_size, void* d_ws, size_t ws_size,
                              hipStream_t stream) {
  const float* x = (const float*)d_in[0];
  const int* wq = (const int*)d_in[1];
  const float* scales = (const float*)d_in[2];
  const float* bias = (const float*)d_in[3];
  float* out = (float*)d_out;

  const size_t xh_bytes = (size_t)M_TOTAL * IN_F * sizeof(half_t);
  const size_t wh_bytes = (size_t)OUT_F * IN_F * sizeof(half_t);

  if (ws_size >= xh_bytes + wh_bytes) {
    half_t* xh = (half_t*)d_ws;
    half_t* wh = (half_t*)((char*)d_ws + xh_bytes);
    convert_x_k<<<2048, 256, 0, stream>>>(x, xh);
    dequant_w_k<<<OUT_F, 512, 0, stream>>>(wq, scales, wh);
    gemm_k<<<(M_TOTAL / BM) * (OUT_F / BN), 512, 0, stream>>>(xh, wh, bias, out);
  } else {
    long total = (long)M_TOTAL * OUT_F;
    naive_k<<<(int)((total + 255) / 256), 256, 0, stream>>>(x, wq, scales, bias, out);
  }
}